// Round 1
// baseline (29.569 us; speedup 1.0000x reference)
//
#include <hip/hip_runtime.h>
#include <math.h>

#define SEARCH 7
#define PAD 3
#define S2 49
#define KNN 7
#define NCLASSES 20
#define H 64
#define W 2048
#define NPTS 131072

struct InvG { float v[S2]; };

__global__ __launch_bounds__(256) void knn_kernel(
    const float* __restrict__ proj_range,
    const float* __restrict__ unproj_range,
    const int* __restrict__ proj_argmax,
    const int* __restrict__ pxv,
    const int* __restrict__ pyv,
    int* __restrict__ outv,
    InvG invg)
{
    int i = blockIdx.x * blockDim.x + threadIdx.x;
    if (i >= NPTS) return;
    int x = pxv[i];
    int y = pyv[i];
    float u = unproj_range[i];

    // 7 smallest keys; key = (float_bits(dist) << 6) | j  (dist >= 0 so bits are monotone)
    unsigned long long keys[KNN];
#pragma unroll
    for (int k = 0; k < KNN; ++k) keys[k] = ~0ull;

#pragma unroll
    for (int dy = -PAD; dy <= PAD; ++dy) {
        int row = y + dy;
        bool vrow = (row >= 0) && (row < H);
        int rbase = row * W;
#pragma unroll
        for (int dx = -PAD; dx <= PAD; ++dx) {
            const int j = (dy + PAD) * SEARCH + (dx + PAD);
            float d;
            if (j == (S2 - 1) / 2) {
                d = 0.0f;   // center: nb replaced by unproj -> |u-u|*invg = 0 exactly
            } else {
                int col = x + dx;
                col += (col < 0) ? W : 0;
                col -= (col >= W) ? W : 0;
                float nb = vrow ? proj_range[rbase + col] : 0.0f;
                nb = (nb < 0.0f) ? __builtin_inff() : nb;
                d = fabsf(nb - u) * invg.v[j];
            }
            unsigned long long key =
                ((unsigned long long)__float_as_uint(d) << 6) | (unsigned)j;
            // find current max slot (keys unique; sentinel ties are interchangeable)
            unsigned long long mv = keys[0]; int mi = 0;
#pragma unroll
            for (int k = 1; k < KNN; ++k) {
                bool gt = keys[k] > mv;
                mv = gt ? keys[k] : mv;
                mi = gt ? k  : mi;
            }
            bool rep = key < mv;
#pragma unroll
            for (int k = 0; k < KNN; ++k)
                keys[k] = (rep && (mi == k)) ? key : keys[k];
        }
    }

    // Gather classes for the winners; dist > 1.0 (incl. inf / sentinel) -> class 20 -> no vote.
    int cls[KNN];
#pragma unroll
    for (int k = 0; k < KNN; ++k) {
        unsigned long long key = keys[k];
        unsigned distbits = (unsigned)(key >> 6);   // sentinel -> 0xFFFFFFFF -> skipped
        int j = (int)(key & 63u);
        int c = 0;                                   // class 0 never votes
        if (distbits <= 0x3f800000u) {               // dist <= CUTOFF (1.0f)
            int dy = j / SEARCH - PAD;
            int dx = j % SEARCH - PAD;
            int row = y + dy;
            bool vrow = (row >= 0) && (row < H);
            int col = x + dx;
            col += (col < 0) ? W : 0;
            col -= (col >= W) ? W : 0;
            c = vrow ? proj_argmax[row * W + col] : 0;
        }
        cls[k] = c;
    }

    // argmax over votes for classes 1..19, ties -> lowest class; zero votes -> class 1
    int best = 0, bestc = 1;
#pragma unroll
    for (int c = 1; c <= NCLASSES - 1; ++c) {
        int cnt = 0;
#pragma unroll
        for (int k = 0; k < KNN; ++k) cnt += (cls[k] == c) ? 1 : 0;
        bool gt = cnt > best;
        best  = gt ? cnt : best;
        bestc = gt ? c   : bestc;
    }
    outv[i] = bestc;
}

extern "C" void kernel_launch(void* const* d_in, const int* in_sizes, int n_in,
                              void* d_out, int out_size, void* d_ws, size_t ws_size,
                              hipStream_t stream) {
    const float* proj_range   = (const float*)d_in[0];
    const float* unproj_range = (const float*)d_in[1];
    const int*   proj_argmax  = (const int*)d_in[2];
    const int*   px           = (const int*)d_in[3];
    const int*   py           = (const int*)d_in[4];
    int* out = (int*)d_out;

    // Emulate numpy float32 pipeline for the inverse-gaussian table.
    InvG invg;
    float g[S2];
    for (int yy = 0; yy < SEARCH; ++yy) {
        for (int xx = 0; xx < SEARCH; ++xx) {
            float fdx = (float)xx - 3.0f;        // exact
            float fdy = (float)yy - 3.0f;        // exact
            float s   = fdx * fdx + fdy * fdy;   // exact small ints
            float arg = -s / 2.0f;               // exact halves
            float e   = (float)exp((double)arg); // ~correctly-rounded f32 exp
            float gg  = e / 6.2831855f;          // float32(2*pi*var)
            g[yy * SEARCH + xx] = gg;
        }
    }
    // numpy pairwise sum, n=49 (<= blocksize 128 path): 8 accumulators + tree + tail
    float r[8];
    for (int t = 0; t < 8; ++t) r[t] = g[t];
    int ii;
    for (ii = 8; ii + 8 <= 48; ii += 8)
        for (int t = 0; t < 8; ++t) r[t] += g[ii + t];
    float ssum = ((r[0] + r[1]) + (r[2] + r[3])) + ((r[4] + r[5]) + (r[6] + r[7]));
    for (; ii < S2; ++ii) ssum += g[ii];

    for (int t = 0; t < S2; ++t) invg.v[t] = 1.0f - (g[t] / ssum);

    const int block = 256;
    const int grid = (NPTS + block - 1) / block;
    knn_kernel<<<grid, block, 0, stream>>>(proj_range, unproj_range, proj_argmax,
                                           px, py, out, invg);
}